// Round 8
// baseline (74.643 us; speedup 1.0000x reference)
//
#include <hip/hip_runtime.h>

#define B_SZ 16
#define N_BOX 96
#define EPSF 1e-7f

// ---- geometry ---------------------------------------------------------------
// level l: wl = hl = 1024 >> l, plane_px = wl*wl (16 planes each)
// corr blocks: per batch 23 = l0:16 chunks, l1:4, l2:1, l3:1, l4:1  -> 368
//   thread-per-mask-word (32 px); chunkWords: 2048,2048,2048,512,128
// stream blocks (2736):
//   l0: 0..2047 (128/plane), l1: 2048..2559 (32/plane), l2: 2560..2687 (8/plane),
//   l3: 2688..2719 (2/plane), l4: 2720..2735 (1/plane)
#define N_CORR3  (23 * B_SZ)
#define N_STREAM 2736

__device__ __forceinline__ const float* pick_att(
    int l, const float* a0, const float* a1, const float* a2,
    const float* a3, const float* a4)
{
    switch (l) { case 0: return a0; case 1: return a1; case 2: return a2;
                 case 3: return a3; default: return a4; }
}

__device__ __forceinline__ float block_reduce(float s, float* wsum) {
    #pragma unroll
    for (int off = 32; off > 0; off >>= 1)
        s += __shfl_down(s, off, 64);
    int lane = threadIdx.x & 63, wv = threadIdx.x >> 6;
    if (lane == 0) wsum[wv] = s;
    __syncthreads();
    return wsum[0] + wsum[1] + wsum[2] + wsum[3];
}

// ---- kernel A: correction — word-parallel union mask, no atomics on px ------
__global__ __launch_bounds__(256)
void corr_kernel(const float* __restrict__ a0, const float* __restrict__ a1,
                 const float* __restrict__ a2, const float* __restrict__ a3,
                 const float* __restrict__ a4,
                 const float* __restrict__ bboxs,
                 const int* __restrict__ hp, const int* __restrict__ wp,
                 float* __restrict__ corr)      // [N_CORR3]
{
    __shared__ int4 rect[N_BOX];                // x1,y1,x2,y2 (compacted)
    __shared__ int Rcnt;
    __shared__ float wsum[4];

    int c = blockIdx.x;
    int b = c / 23, k = c % 23;
    int l, chunk;
    if (k < 16)      { l = 0; chunk = k; }
    else if (k < 20) { l = 1; chunk = k - 16; }
    else             { l = k - 18; chunk = 0; }          // k=20,21,22 -> l=2,3,4

    const float* att = pick_att(l, a0, a1, a2, a3, a4);
    int wl = 1024 >> l;
    int wprShift = 5 - l;                        // wpr = wl/32
    int wordsPlane = 1 << (15 - 2 * l);
    int chunkWords = (l == 0) ? 2048 : (l == 1) ? 2048 :
                     (l == 2) ? 2048 : (l == 3) ? 512 : 128;
    int word0 = chunk * chunkWords;
    float Wf = (float)(*wp), Hf = (float)(*hp);
    (void)wordsPlane;

    if (threadIdx.x == 0) Rcnt = 0;
    __syncthreads();

    // gate boxes, compact active rects (one lane per box; order-independent)
    if (threadIdx.x < N_BOX) {
        int n = threadIdx.x;
        const float* bx = bboxs + (b * N_BOX + n) * 5;
        float x1 = bx[0], y1 = bx[1], x2 = bx[2], y2 = bx[3], lb = bx[4];
        double based = (double)(32 << l);
        float mn  = (float)(based * based * 0.5);
        float mxv = (float)((based * 1.58) * (based * 1.58) * 2.0);
        float area = (x2 - x1) * (y2 - y1);
        bool ok = (lb != -1.0f) && (x1 <= Wf) && (y1 <= Hf) &&
                  (x2 <= Wf) && (y2 <= Hf) && (area >= mn) && (area <= mxv);
        float sx = (float)wl / Wf, sy = (float)wl / Hf;
        int ix1 = (int)fmaxf(floorf(x1 * sx), 0.0f);
        int iy1 = (int)fmaxf(floorf(y1 * sy), 0.0f);
        int ix2 = (int)fminf(ceilf(x2 * sx) + 1.0f, (float)wl);
        int iy2 = (int)fminf(ceilf(y2 * sy) + 1.0f, (float)wl);
        if (ok && ix2 > ix1 && iy2 > iy1) {
            int i = atomicAdd(&Rcnt, 1);
            rect[i] = make_int4(ix1, iy1, ix2, iy2);
        }
    }
    __syncthreads();

    int Rc = Rcnt;
    unsigned pbase = (unsigned)b << (20 - 2 * l);
    float s = 0.0f;

    // thread-per-word: build union mask arithmetically, then scan set bits
    for (int j = word0 + (int)threadIdx.x; j < word0 + chunkWords; j += 256) {
        int y = j >> wprShift;
        int xbase = (j & ((1 << wprShift) - 1)) << 5;
        unsigned m = 0u;
        for (int r = 0; r < Rc; ++r) {
            int4 rc = rect[r];                   // uniform LDS broadcast
            bool inRow = (y >= rc.y) && (y < rc.w);
            int lo = max(rc.x - xbase, 0);
            int hi = min(rc.z - xbase, 32);
            if (inRow && lo < hi) {
                unsigned wm = ((hi >= 32) ? 0xffffffffu : ((1u << hi) - 1u))
                            & ~((lo <= 0) ? 0u : ((1u << lo) - 1u));
                m |= wm;
            }
        }
        unsigned base = pbase + (unsigned)y * (unsigned)wl + (unsigned)xbase;
        while (m) {
            int bit = __ffs(m) - 1;
            m &= m - 1u;
            float p = att[base + (unsigned)bit];
            p = fminf(fmaxf(p, EPSF), 1.0f - EPSF);
            s += __logf((1.0f - p) / p);         // -log(p) + log(1-p)
        }
    }

    float t = block_reduce(s, wsum);
    if (threadIdx.x == 0) corr[c] = t;
}

// ---- kernel B: pure streaming sum of -log(1-p)  (UNCHANGED from R7) ---------
__global__ __launch_bounds__(256)
void stream_kernel(const float* __restrict__ a0, const float* __restrict__ a1,
                   const float* __restrict__ a2, const float* __restrict__ a3,
                   const float* __restrict__ a4,
                   float* __restrict__ partial)   // [N_STREAM]
{
    __shared__ float wsum[4];
    int sbid = blockIdx.x;
    int l, start, bppShift;
    const float* att;
    if (sbid < 2048)      { l = 0; start = 0;    bppShift = 7; att = a0; }
    else if (sbid < 2560) { l = 1; start = 2048; bppShift = 5; att = a1; }
    else if (sbid < 2688) { l = 2; start = 2560; bppShift = 3; att = a2; }
    else if (sbid < 2720) { l = 3; start = 2688; bppShift = 1; att = a3; }
    else                  { l = 4; start = 2720; bppShift = 0; att = a4; }

    int planeF4 = 1 << (18 - 2 * l);
    int bil = sbid - start;
    int chunk = bil & ((1 << bppShift) - 1);
    int nf4 = planeF4 >> bppShift;              // 2048, or 1024 at l4
    unsigned gf4base = (unsigned)(bil >> bppShift) * (unsigned)planeF4
                     + (unsigned)chunk * (unsigned)nf4 + threadIdx.x;

    float s = 0.0f;
    if (nf4 == 2048) {
        float4 av[8];
        #pragma unroll
        for (int u = 0; u < 8; ++u)
            av[u] = reinterpret_cast<const float4*>(att)[gf4base + u * 256u];
        #pragma unroll
        for (int u = 0; u < 8; ++u) {
            float q0 = 1.0f - fminf(fmaxf(av[u].x, EPSF), 1.0f - EPSF);
            float q1 = 1.0f - fminf(fmaxf(av[u].y, EPSF), 1.0f - EPSF);
            float q2 = 1.0f - fminf(fmaxf(av[u].z, EPSF), 1.0f - EPSF);
            float q3 = 1.0f - fminf(fmaxf(av[u].w, EPSF), 1.0f - EPSF);
            s -= __logf((q0 * q1) * (q2 * q3));     // >= 1e-28, no underflow
        }
    } else {
        float4 av[4];
        #pragma unroll
        for (int u = 0; u < 4; ++u)
            av[u] = reinterpret_cast<const float4*>(att)[gf4base + u * 256u];
        #pragma unroll
        for (int u = 0; u < 4; ++u) {
            float q0 = 1.0f - fminf(fmaxf(av[u].x, EPSF), 1.0f - EPSF);
            float q1 = 1.0f - fminf(fmaxf(av[u].y, EPSF), 1.0f - EPSF);
            float q2 = 1.0f - fminf(fmaxf(av[u].z, EPSF), 1.0f - EPSF);
            float q3 = 1.0f - fminf(fmaxf(av[u].w, EPSF), 1.0f - EPSF);
            s -= __logf((q0 * q1) * (q2 * q3));
        }
    }

    float t = block_reduce(s, wsum);
    if (threadIdx.x == 0) partial[sbid] = t;
}

// ---- kernel C: finalize ------------------------------------------------------
__global__ __launch_bounds__(256)
void finalize_kernel(const float* __restrict__ bboxs,
                     const int* __restrict__ hp, const int* __restrict__ wp,
                     const float* __restrict__ partial,
                     const float* __restrict__ corr,
                     float* __restrict__ out)
{
    __shared__ int hasbox[B_SZ];
    __shared__ double red[256];
    if (threadIdx.x < B_SZ) hasbox[threadIdx.x] = 0;
    __syncthreads();
    float Wf = (float)(*wp), Hf = (float)(*hp);
    for (int i = (int)threadIdx.x; i < B_SZ * N_BOX; i += 256) {
        const float* bx = bboxs + i * 5;
        if (bx[4] != -1.0f && bx[0] <= Wf && bx[1] <= Hf && bx[2] <= Wf && bx[3] <= Hf)
            hasbox[i / N_BOX] = 1;        // benign race, same value
    }
    __syncthreads();

    double t = 0.0;
    for (int i = (int)threadIdx.x; i < N_STREAM; i += 256) {
        int l, start, bppShift;
        if (i < 2048)      { l = 0; start = 0;    bppShift = 7; }
        else if (i < 2560) { l = 1; start = 2048; bppShift = 5; }
        else if (i < 2688) { l = 2; start = 2560; bppShift = 3; }
        else if (i < 2720) { l = 3; start = 2688; bppShift = 1; }
        else               { l = 4; start = 2720; bppShift = 0; }
        int b = (i - start) >> bppShift;
        if (hasbox[b]) {
            int wl = 1024 >> l;
            t += (double)partial[i] / (double)(wl * wl);
        }
    }
    for (int i = (int)threadIdx.x; i < N_CORR3; i += 256) {
        int b = i / 23, k = i % 23;
        int l = (k < 16) ? 0 : (k < 20) ? 1 : (k - 18);
        if (hasbox[b]) {
            int wl = 1024 >> l;
            t += (double)corr[i] / (double)(wl * wl);
        }
    }
    red[threadIdx.x] = t;
    __syncthreads();
    for (int off = 128; off > 0; off >>= 1) {
        if ((int)threadIdx.x < off) red[threadIdx.x] += red[threadIdx.x + off];
        __syncthreads();
    }
    if (threadIdx.x == 0)
        out[0] = (float)(red[0] / (5.0 * (double)B_SZ));
}

// ---- launch ------------------------------------------------------------------
extern "C" void kernel_launch(void* const* d_in, const int* in_sizes, int n_in,
                              void* d_out, int out_size, void* d_ws, size_t ws_size,
                              hipStream_t stream)
{
    const float* a0 = (const float*)d_in[0];
    const float* a1 = (const float*)d_in[1];
    const float* a2 = (const float*)d_in[2];
    const float* a3 = (const float*)d_in[3];
    const float* a4 = (const float*)d_in[4];
    const float* bboxs = (const float*)d_in[5];
    const int* hp = (const int*)d_in[6];
    const int* wp = (const int*)d_in[7];

    float* partial = (float*)d_ws;            // N_STREAM floats, all written
    float* corr    = partial + N_STREAM;      // N_CORR3 floats, all written

    corr_kernel<<<N_CORR3, 256, 0, stream>>>(a0, a1, a2, a3, a4,
                                             bboxs, hp, wp, corr);
    stream_kernel<<<N_STREAM, 256, 0, stream>>>(a0, a1, a2, a3, a4, partial);
    finalize_kernel<<<1, 256, 0, stream>>>(bboxs, hp, wp, partial, corr,
                                           (float*)d_out);
}

// Round 9
// 59.069 us; speedup vs baseline: 1.2636x; 1.2636x over previous
//
#include <hip/hip_runtime.h>

#define B_SZ 16
#define N_BOX 96
#define EPSF 1e-7f

// ---- geometry ---------------------------------------------------------------
// level l: wl = hl = 1024 >> l, plane_px = wl*wl (16 planes each)
// corr blocks: 80, one per (b,l). (rect,row)-pair parallel, 64-bit reg masks.
// stream blocks (2736):
//   l0: 0..2047 (128/plane), l1: 2048..2559 (32/plane), l2: 2560..2687 (8/plane),
//   l3: 2688..2719 (2/plane), l4: 2720..2735 (1/plane)
#define N_CORR   (B_SZ * 5)
#define N_STREAM 2736

__device__ __forceinline__ const float* pick_att(
    int l, const float* a0, const float* a1, const float* a2,
    const float* a3, const float* a4)
{
    switch (l) { case 0: return a0; case 1: return a1; case 2: return a2;
                 case 3: return a3; default: return a4; }
}

__device__ __forceinline__ float block_reduce(float s, float* wsum) {
    #pragma unroll
    for (int off = 32; off > 0; off >>= 1)
        s += __shfl_down(s, off, 64);
    int lane = threadIdx.x & 63, wv = threadIdx.x >> 6;
    if (lane == 0) wsum[wv] = s;
    __syncthreads();
    return wsum[0] + wsum[1] + wsum[2] + wsum[3];
}

__device__ __forceinline__ unsigned long long bits64(int lo, int hi) {
    // assumes 0 <= lo < hi <= 64
    unsigned long long top = (hi >= 64) ? ~0ULL : ((1ULL << hi) - 1ULL);
    return top & ~((1ULL << lo) - 1ULL);
}

// ---- kernel A: correction — (rect,row)-pair parallel, first-hit dedup -------
__global__ __launch_bounds__(256)
void corr_kernel(const float* __restrict__ a0, const float* __restrict__ a1,
                 const float* __restrict__ a2, const float* __restrict__ a3,
                 const float* __restrict__ a4,
                 const float* __restrict__ bboxs,
                 const int* __restrict__ hp, const int* __restrict__ wp,
                 float* __restrict__ corr)      // [N_CORR]
{
    __shared__ int4 rect[N_BOX];                // x1,y1,x2,y2 (compacted)
    __shared__ int Rcnt;
    __shared__ float wsum[4];

    int c = blockIdx.x;
    int b = c / 5, l = c % 5;
    const float* att = pick_att(l, a0, a1, a2, a3, a4);
    int wl = 1024 >> l;
    float Wf = (float)(*wp), Hf = (float)(*hp);

    if (threadIdx.x == 0) Rcnt = 0;
    __syncthreads();

    // gate boxes, compact active rects (one lane per box; order-independent)
    if (threadIdx.x < N_BOX) {
        int n = threadIdx.x;
        const float* bx = bboxs + (b * N_BOX + n) * 5;
        float x1 = bx[0], y1 = bx[1], x2 = bx[2], y2 = bx[3], lb = bx[4];
        double based = (double)(32 << l);
        float mn  = (float)(based * based * 0.5);
        float mxv = (float)((based * 1.58) * (based * 1.58) * 2.0);
        float area = (x2 - x1) * (y2 - y1);
        bool ok = (lb != -1.0f) && (x1 <= Wf) && (y1 <= Hf) &&
                  (x2 <= Wf) && (y2 <= Hf) && (area >= mn) && (area <= mxv);
        float sx = (float)wl / Wf, sy = (float)wl / Hf;
        int ix1 = (int)fmaxf(floorf(x1 * sx), 0.0f);
        int iy1 = (int)fmaxf(floorf(y1 * sy), 0.0f);
        int ix2 = (int)fminf(ceilf(x2 * sx) + 1.0f, (float)wl);
        int iy2 = (int)fminf(ceilf(y2 * sy) + 1.0f, (float)wl);
        if (ok && ix2 > ix1 && iy2 > iy1) {
            int i = atomicAdd(&Rcnt, 1);
            rect[i] = make_int4(ix1, iy1, ix2, iy2);
        }
    }
    __syncthreads();

    int Rc = Rcnt;
    unsigned pbase = (unsigned)b << (20 - 2 * l);
    float s = 0.0f;

    // pair = (rect r, row slot). Rect sides are ~6..22 px at every level
    // (level gate ties box size to level scale), so one 64-bit window and one
    // row-slot iteration is the common case; loops keep it exact for any data.
    for (int pair = (int)threadIdx.x; pair < Rc * 32; pair += 256) {
        int r = pair >> 5, row = pair & 31;
        int4 rc = rect[r];
        for (int y = rc.y + row; y < rc.w; y += 32) {
            int xb0 = rc.x & ~31;
            for (int xb = xb0; xb < rc.z; xb += 64) {
                int lo = max(rc.x - xb, 0), hi = min(rc.z - xb, 64);
                unsigned long long m = bits64(lo, hi);
                // subtract earlier rects covering this row (first-hit dedup)
                for (int q = 0; q < r; ++q) {
                    int4 qc = rect[q];            // LDS broadcast, pipelined
                    bool inRow = (y >= qc.y) && (y < qc.w);
                    int ql = max(qc.x - xb, 0), qh = min(qc.z - xb, 64);
                    if (inRow && ql < qh) m &= ~bits64(ql, qh);
                }
                unsigned rowbase = pbase + (unsigned)y * (unsigned)wl
                                 + (unsigned)xb;
                while (m) {
                    int bit = __ffsll((unsigned long long)m) - 1;
                    m &= m - 1ULL;
                    float p = att[rowbase + (unsigned)bit];
                    p = fminf(fmaxf(p, EPSF), 1.0f - EPSF);
                    s += __logf((1.0f - p) / p);  // -log(p) + log(1-p)
                }
            }
        }
    }

    float t = block_reduce(s, wsum);
    if (threadIdx.x == 0) corr[c] = t;
}

// ---- kernel B: pure streaming sum of -log(1-p)  (UNCHANGED) -----------------
__global__ __launch_bounds__(256)
void stream_kernel(const float* __restrict__ a0, const float* __restrict__ a1,
                   const float* __restrict__ a2, const float* __restrict__ a3,
                   const float* __restrict__ a4,
                   float* __restrict__ partial)   // [N_STREAM]
{
    __shared__ float wsum[4];
    int sbid = blockIdx.x;
    int l, start, bppShift;
    const float* att;
    if (sbid < 2048)      { l = 0; start = 0;    bppShift = 7; att = a0; }
    else if (sbid < 2560) { l = 1; start = 2048; bppShift = 5; att = a1; }
    else if (sbid < 2688) { l = 2; start = 2560; bppShift = 3; att = a2; }
    else if (sbid < 2720) { l = 3; start = 2688; bppShift = 1; att = a3; }
    else                  { l = 4; start = 2720; bppShift = 0; att = a4; }

    int planeF4 = 1 << (18 - 2 * l);
    int bil = sbid - start;
    int chunk = bil & ((1 << bppShift) - 1);
    int nf4 = planeF4 >> bppShift;              // 2048, or 1024 at l4
    unsigned gf4base = (unsigned)(bil >> bppShift) * (unsigned)planeF4
                     + (unsigned)chunk * (unsigned)nf4 + threadIdx.x;

    float s = 0.0f;
    if (nf4 == 2048) {
        float4 av[8];
        #pragma unroll
        for (int u = 0; u < 8; ++u)
            av[u] = reinterpret_cast<const float4*>(att)[gf4base + u * 256u];
        #pragma unroll
        for (int u = 0; u < 8; ++u) {
            float q0 = 1.0f - fminf(fmaxf(av[u].x, EPSF), 1.0f - EPSF);
            float q1 = 1.0f - fminf(fmaxf(av[u].y, EPSF), 1.0f - EPSF);
            float q2 = 1.0f - fminf(fmaxf(av[u].z, EPSF), 1.0f - EPSF);
            float q3 = 1.0f - fminf(fmaxf(av[u].w, EPSF), 1.0f - EPSF);
            s -= __logf((q0 * q1) * (q2 * q3));     // >= 1e-28, no underflow
        }
    } else {
        float4 av[4];
        #pragma unroll
        for (int u = 0; u < 4; ++u)
            av[u] = reinterpret_cast<const float4*>(att)[gf4base + u * 256u];
        #pragma unroll
        for (int u = 0; u < 4; ++u) {
            float q0 = 1.0f - fminf(fmaxf(av[u].x, EPSF), 1.0f - EPSF);
            float q1 = 1.0f - fminf(fmaxf(av[u].y, EPSF), 1.0f - EPSF);
            float q2 = 1.0f - fminf(fmaxf(av[u].z, EPSF), 1.0f - EPSF);
            float q3 = 1.0f - fminf(fmaxf(av[u].w, EPSF), 1.0f - EPSF);
            s -= __logf((q0 * q1) * (q2 * q3));
        }
    }

    float t = block_reduce(s, wsum);
    if (threadIdx.x == 0) partial[sbid] = t;
}

// ---- kernel C: finalize ------------------------------------------------------
__global__ __launch_bounds__(256)
void finalize_kernel(const float* __restrict__ bboxs,
                     const int* __restrict__ hp, const int* __restrict__ wp,
                     const float* __restrict__ partial,
                     const float* __restrict__ corr,
                     float* __restrict__ out)
{
    __shared__ int hasbox[B_SZ];
    __shared__ double red[256];
    if (threadIdx.x < B_SZ) hasbox[threadIdx.x] = 0;
    __syncthreads();
    float Wf = (float)(*wp), Hf = (float)(*hp);
    for (int i = (int)threadIdx.x; i < B_SZ * N_BOX; i += 256) {
        const float* bx = bboxs + i * 5;
        if (bx[4] != -1.0f && bx[0] <= Wf && bx[1] <= Hf && bx[2] <= Wf && bx[3] <= Hf)
            hasbox[i / N_BOX] = 1;        // benign race, same value
    }
    __syncthreads();

    double t = 0.0;
    for (int i = (int)threadIdx.x; i < N_STREAM; i += 256) {
        int l, start, bppShift;
        if (i < 2048)      { l = 0; start = 0;    bppShift = 7; }
        else if (i < 2560) { l = 1; start = 2048; bppShift = 5; }
        else if (i < 2688) { l = 2; start = 2560; bppShift = 3; }
        else if (i < 2720) { l = 3; start = 2688; bppShift = 1; }
        else               { l = 4; start = 2720; bppShift = 0; }
        int b = (i - start) >> bppShift;
        if (hasbox[b]) {
            int wl = 1024 >> l;
            t += (double)partial[i] / (double)(wl * wl);
        }
    }
    for (int i = (int)threadIdx.x; i < N_CORR; i += 256) {
        int b = i / 5, l = i % 5;
        if (hasbox[b]) {
            int wl = 1024 >> l;
            t += (double)corr[i] / (double)(wl * wl);
        }
    }
    red[threadIdx.x] = t;
    __syncthreads();
    for (int off = 128; off > 0; off >>= 1) {
        if ((int)threadIdx.x < off) red[threadIdx.x] += red[threadIdx.x + off];
        __syncthreads();
    }
    if (threadIdx.x == 0)
        out[0] = (float)(red[0] / (5.0 * (double)B_SZ));
}

// ---- launch ------------------------------------------------------------------
extern "C" void kernel_launch(void* const* d_in, const int* in_sizes, int n_in,
                              void* d_out, int out_size, void* d_ws, size_t ws_size,
                              hipStream_t stream)
{
    const float* a0 = (const float*)d_in[0];
    const float* a1 = (const float*)d_in[1];
    const float* a2 = (const float*)d_in[2];
    const float* a3 = (const float*)d_in[3];
    const float* a4 = (const float*)d_in[4];
    const float* bboxs = (const float*)d_in[5];
    const int* hp = (const int*)d_in[6];
    const int* wp = (const int*)d_in[7];

    float* partial = (float*)d_ws;            // N_STREAM floats, all written
    float* corr    = partial + N_STREAM;      // N_CORR floats, all written

    corr_kernel<<<N_CORR, 256, 0, stream>>>(a0, a1, a2, a3, a4,
                                            bboxs, hp, wp, corr);
    stream_kernel<<<N_STREAM, 256, 0, stream>>>(a0, a1, a2, a3, a4, partial);
    finalize_kernel<<<1, 256, 0, stream>>>(bboxs, hp, wp, partial, corr,
                                           (float*)d_out);
}

// Round 10
// 50.916 us; speedup vs baseline: 1.4660x; 1.1601x over previous
//
#include <hip/hip_runtime.h>

#define B_SZ 16
#define N_BOX 96
#define EPSF 1e-7f

// ---- geometry ---------------------------------------------------------------
// level l: wl = hl = 1024 >> l, plane_px = wl*wl (16 planes each)
// corr blocks: 80, one per (b,l). (rect,row)-pair parallel, batched 32-px loads.
// stream blocks (2736):
//   l0: 0..2047 (128/plane), l1: 2048..2559 (32/plane), l2: 2560..2687 (8/plane),
//   l3: 2688..2719 (2/plane), l4: 2720..2735 (1/plane)
#define N_CORR   (B_SZ * 5)
#define N_STREAM 2736

__device__ __forceinline__ const float* pick_att(
    int l, const float* a0, const float* a1, const float* a2,
    const float* a3, const float* a4)
{
    switch (l) { case 0: return a0; case 1: return a1; case 2: return a2;
                 case 3: return a3; default: return a4; }
}

__device__ __forceinline__ float block_reduce(float s, float* wsum) {
    #pragma unroll
    for (int off = 32; off > 0; off >>= 1)
        s += __shfl_down(s, off, 64);
    int lane = threadIdx.x & 63, wv = threadIdx.x >> 6;
    if (lane == 0) wsum[wv] = s;
    __syncthreads();
    return wsum[0] + wsum[1] + wsum[2] + wsum[3];
}

__device__ __forceinline__ unsigned bits32(int lo, int hi) {
    // assumes 0 <= lo < hi <= 32
    unsigned top = (hi >= 32) ? 0xffffffffu : ((1u << hi) - 1u);
    return top & ~((1u << lo) - 1u);
}

// ---- kernel A: pure streaming sum of -log(1-p)  (UNCHANGED, runs FIRST) -----
__global__ __launch_bounds__(256)
void stream_kernel(const float* __restrict__ a0, const float* __restrict__ a1,
                   const float* __restrict__ a2, const float* __restrict__ a3,
                   const float* __restrict__ a4,
                   float* __restrict__ partial)   // [N_STREAM]
{
    __shared__ float wsum[4];
    int sbid = blockIdx.x;
    int l, start, bppShift;
    const float* att;
    if (sbid < 2048)      { l = 0; start = 0;    bppShift = 7; att = a0; }
    else if (sbid < 2560) { l = 1; start = 2048; bppShift = 5; att = a1; }
    else if (sbid < 2688) { l = 2; start = 2560; bppShift = 3; att = a2; }
    else if (sbid < 2720) { l = 3; start = 2688; bppShift = 1; att = a3; }
    else                  { l = 4; start = 2720; bppShift = 0; att = a4; }

    int planeF4 = 1 << (18 - 2 * l);
    int bil = sbid - start;
    int chunk = bil & ((1 << bppShift) - 1);
    int nf4 = planeF4 >> bppShift;              // 2048, or 1024 at l4
    unsigned gf4base = (unsigned)(bil >> bppShift) * (unsigned)planeF4
                     + (unsigned)chunk * (unsigned)nf4 + threadIdx.x;

    float s = 0.0f;
    if (nf4 == 2048) {
        float4 av[8];
        #pragma unroll
        for (int u = 0; u < 8; ++u)
            av[u] = reinterpret_cast<const float4*>(att)[gf4base + u * 256u];
        #pragma unroll
        for (int u = 0; u < 8; ++u) {
            float q0 = 1.0f - fminf(fmaxf(av[u].x, EPSF), 1.0f - EPSF);
            float q1 = 1.0f - fminf(fmaxf(av[u].y, EPSF), 1.0f - EPSF);
            float q2 = 1.0f - fminf(fmaxf(av[u].z, EPSF), 1.0f - EPSF);
            float q3 = 1.0f - fminf(fmaxf(av[u].w, EPSF), 1.0f - EPSF);
            s -= __logf((q0 * q1) * (q2 * q3));     // >= 1e-28, no underflow
        }
    } else {
        float4 av[4];
        #pragma unroll
        for (int u = 0; u < 4; ++u)
            av[u] = reinterpret_cast<const float4*>(att)[gf4base + u * 256u];
        #pragma unroll
        for (int u = 0; u < 4; ++u) {
            float q0 = 1.0f - fminf(fmaxf(av[u].x, EPSF), 1.0f - EPSF);
            float q1 = 1.0f - fminf(fmaxf(av[u].y, EPSF), 1.0f - EPSF);
            float q2 = 1.0f - fminf(fmaxf(av[u].z, EPSF), 1.0f - EPSF);
            float q3 = 1.0f - fminf(fmaxf(av[u].w, EPSF), 1.0f - EPSF);
            s -= __logf((q0 * q1) * (q2 * q3));
        }
    }

    float t = block_reduce(s, wsum);
    if (threadIdx.x == 0) partial[sbid] = t;
}

// ---- kernel B: correction — batched loads, mask-weighted logs ----------------
__global__ __launch_bounds__(256)
void corr_kernel(const float* __restrict__ a0, const float* __restrict__ a1,
                 const float* __restrict__ a2, const float* __restrict__ a3,
                 const float* __restrict__ a4,
                 const float* __restrict__ bboxs,
                 const int* __restrict__ hp, const int* __restrict__ wp,
                 float* __restrict__ corr)      // [N_CORR]
{
    __shared__ int4 rect[N_BOX];                // x1,y1,x2,y2 (compacted)
    __shared__ int Rcnt;
    __shared__ float wsum[4];

    int c = blockIdx.x;
    int b = c / 5, l = c % 5;
    const float* att = pick_att(l, a0, a1, a2, a3, a4);
    int wl = 1024 >> l;
    unsigned maxIdx = ((unsigned)B_SZ << (20 - 2 * l)) - 1u;
    float Wf = (float)(*wp), Hf = (float)(*hp);

    if (threadIdx.x == 0) Rcnt = 0;
    __syncthreads();

    // gate boxes, compact active rects (one lane per box; order-independent:
    // first-hit dedup makes the union a set regardless of compaction order)
    if (threadIdx.x < N_BOX) {
        int n = threadIdx.x;
        const float* bx = bboxs + (b * N_BOX + n) * 5;
        float x1 = bx[0], y1 = bx[1], x2 = bx[2], y2 = bx[3], lb = bx[4];
        double based = (double)(32 << l);
        float mn  = (float)(based * based * 0.5);
        float mxv = (float)((based * 1.58) * (based * 1.58) * 2.0);
        float area = (x2 - x1) * (y2 - y1);
        bool ok = (lb != -1.0f) && (x1 <= Wf) && (y1 <= Hf) &&
                  (x2 <= Wf) && (y2 <= Hf) && (area >= mn) && (area <= mxv);
        float sx = (float)wl / Wf, sy = (float)wl / Hf;
        int ix1 = (int)fmaxf(floorf(x1 * sx), 0.0f);
        int iy1 = (int)fmaxf(floorf(y1 * sy), 0.0f);
        int ix2 = (int)fminf(ceilf(x2 * sx) + 1.0f, (float)wl);
        int iy2 = (int)fminf(ceilf(y2 * sy) + 1.0f, (float)wl);
        if (ok && ix2 > ix1 && iy2 > iy1) {
            int i = atomicAdd(&Rcnt, 1);
            rect[i] = make_int4(ix1, iy1, ix2, iy2);
        }
    }
    __syncthreads();

    int Rc = Rcnt;
    unsigned pbase = (unsigned)b << (20 - 2 * l);
    float s = 0.0f;

    // pair = (rect r, row slot). Typical rect is ~7..27 px/side at every level
    // (the area gate ties box size to level scale), so one row iteration and
    // one 32-px window is the common case; the loops keep any data exact.
    for (int pair = (int)threadIdx.x; pair < Rc * 32; pair += 256) {
        int r = pair >> 5, row = pair & 31;
        int4 rc = rect[r];
        int wpx = rc.z - rc.x;
        for (int y = rc.y + row; y < rc.w; y += 32) {
            unsigned rowbase = pbase + (unsigned)y * (unsigned)wl + (unsigned)rc.x;
            for (int xoff = 0; xoff < wpx; xoff += 32) {
                // window = [rc.x+xoff, rc.x+xoff+32); base interval of rect
                unsigned m = bits32(0, min(wpx - xoff, 32));
                for (int q = 0; q < r; ++q) {      // first-hit dedup (union)
                    int4 qc = rect[q];             // uniform LDS broadcast
                    bool inRow = (y >= qc.y) && (y < qc.w);
                    int ql = max(qc.x - rc.x - xoff, 0);
                    int qh = min(qc.z - rc.x - xoff, 32);
                    if (inRow && ql < qh) m &= ~bits32(ql, qh);
                }
                if (!m) continue;
                // batched independent loads: issue all 32, single wait
                float px[32];
                #pragma unroll
                for (int i = 0; i < 32; ++i) {
                    unsigned a = rowbase + (unsigned)(xoff + i);
                    px[i] = att[a < maxIdx ? a : maxIdx];
                }
                #pragma unroll
                for (int i = 0; i < 32; ++i) {
                    float wt = (float)((m >> i) & 1u);
                    float p = fminf(fmaxf(px[i], EPSF), 1.0f - EPSF);
                    s = fmaf(wt, __logf((1.0f - p) / p), s);
                }
            }
        }
    }

    float t = block_reduce(s, wsum);
    if (threadIdx.x == 0) corr[c] = t;
}

// ---- kernel C: finalize ------------------------------------------------------
__global__ __launch_bounds__(256)
void finalize_kernel(const float* __restrict__ bboxs,
                     const int* __restrict__ hp, const int* __restrict__ wp,
                     const float* __restrict__ partial,
                     const float* __restrict__ corr,
                     float* __restrict__ out)
{
    __shared__ int hasbox[B_SZ];
    __shared__ double red[256];
    if (threadIdx.x < B_SZ) hasbox[threadIdx.x] = 0;
    __syncthreads();
    float Wf = (float)(*wp), Hf = (float)(*hp);
    for (int i = (int)threadIdx.x; i < B_SZ * N_BOX; i += 256) {
        const float* bx = bboxs + i * 5;
        if (bx[4] != -1.0f && bx[0] <= Wf && bx[1] <= Hf && bx[2] <= Wf && bx[3] <= Hf)
            hasbox[i / N_BOX] = 1;        // benign race, same value
    }
    __syncthreads();

    double t = 0.0;
    for (int i = (int)threadIdx.x; i < N_STREAM; i += 256) {
        int l, start, bppShift;
        if (i < 2048)      { l = 0; start = 0;    bppShift = 7; }
        else if (i < 2560) { l = 1; start = 2048; bppShift = 5; }
        else if (i < 2688) { l = 2; start = 2560; bppShift = 3; }
        else if (i < 2720) { l = 3; start = 2688; bppShift = 1; }
        else               { l = 4; start = 2720; bppShift = 0; }
        int b = (i - start) >> bppShift;
        if (hasbox[b]) {
            int wl = 1024 >> l;
            t += (double)partial[i] / (double)(wl * wl);
        }
    }
    for (int i = (int)threadIdx.x; i < N_CORR; i += 256) {
        int b = i / 5, l = i % 5;
        if (hasbox[b]) {
            int wl = 1024 >> l;
            t += (double)corr[i] / (double)(wl * wl);
        }
    }
    red[threadIdx.x] = t;
    __syncthreads();
    for (int off = 128; off > 0; off >>= 1) {
        if ((int)threadIdx.x < off) red[threadIdx.x] += red[threadIdx.x + off];
        __syncthreads();
    }
    if (threadIdx.x == 0)
        out[0] = (float)(red[0] / (5.0 * (double)B_SZ));
}

// ---- launch ------------------------------------------------------------------
extern "C" void kernel_launch(void* const* d_in, const int* in_sizes, int n_in,
                              void* d_out, int out_size, void* d_ws, size_t ws_size,
                              hipStream_t stream)
{
    const float* a0 = (const float*)d_in[0];
    const float* a1 = (const float*)d_in[1];
    const float* a2 = (const float*)d_in[2];
    const float* a3 = (const float*)d_in[3];
    const float* a4 = (const float*)d_in[4];
    const float* bboxs = (const float*)d_in[5];
    const int* hp = (const int*)d_in[6];
    const int* wp = (const int*)d_in[7];

    float* partial = (float*)d_ws;            // N_STREAM floats, all written
    float* corr    = partial + N_STREAM;      // N_CORR floats, all written

    stream_kernel<<<N_STREAM, 256, 0, stream>>>(a0, a1, a2, a3, a4, partial);
    corr_kernel<<<N_CORR, 256, 0, stream>>>(a0, a1, a2, a3, a4,
                                            bboxs, hp, wp, corr);
    finalize_kernel<<<1, 256, 0, stream>>>(bboxs, hp, wp, partial, corr,
                                           (float*)d_out);
}

// Round 11
// 41.543 us; speedup vs baseline: 1.7968x; 1.2256x over previous
//
#include <hip/hip_runtime.h>

#define B_SZ 16
#define N_BOX 96
#define EPSF 1e-7f

// ---- geometry ---------------------------------------------------------------
// level l: wl = hl = 1024 >> l, plane_px = wl*wl (16 planes each)
// fused grid: bids 0..79 = corr (one per (b,l), dispatched first, overlaps);
//             bids 80..2815 = stream, sbid = bid-80:
//   l0: 0..2047 (128/plane), l1: 2048..2559 (32/plane), l2: 2560..2687 (8/plane),
//   l3: 2688..2719 (2/plane), l4: 2720..2735 (1/plane)
#define N_CORR   (B_SZ * 5)
#define N_STREAM 2736
#define N_BLOCKS (N_CORR + N_STREAM)

__device__ __forceinline__ const float* pick_att(
    int l, const float* a0, const float* a1, const float* a2,
    const float* a3, const float* a4)
{
    switch (l) { case 0: return a0; case 1: return a1; case 2: return a2;
                 case 3: return a3; default: return a4; }
}

__device__ __forceinline__ float block_reduce(float s, float* wsum) {
    #pragma unroll
    for (int off = 32; off > 0; off >>= 1)
        s += __shfl_down(s, off, 64);
    int lane = threadIdx.x & 63, wv = threadIdx.x >> 6;
    if (lane == 0) wsum[wv] = s;
    __syncthreads();
    return wsum[0] + wsum[1] + wsum[2] + wsum[3];
}

__device__ __forceinline__ unsigned bits32(int lo, int hi) {
    // assumes 0 <= lo < hi <= 32
    unsigned top = (hi >= 32) ? 0xffffffffu : ((1u << hi) - 1u);
    return top & ~((1u << lo) - 1u);
}

// ---- kernel 1: fused  corr (bids 0..79) || stream (bids 80..2815) -----------
__global__ __launch_bounds__(256)
void fused_kernel(const float* __restrict__ a0, const float* __restrict__ a1,
                  const float* __restrict__ a2, const float* __restrict__ a3,
                  const float* __restrict__ a4,
                  const float* __restrict__ bboxs,
                  const int* __restrict__ hp, const int* __restrict__ wp,
                  float* __restrict__ partial,   // [N_STREAM]
                  float* __restrict__ corr)      // [N_CORR]
{
    __shared__ float wsum[4];
    int bid = blockIdx.x;
    float s = 0.0f;

    if (bid >= N_CORR) {
        // ---------------- streaming: sum -log(1-p) (UNCHANGED) ---------------
        int sbid = bid - N_CORR;
        int l, start, bppShift;
        const float* att;
        if (sbid < 2048)      { l = 0; start = 0;    bppShift = 7; att = a0; }
        else if (sbid < 2560) { l = 1; start = 2048; bppShift = 5; att = a1; }
        else if (sbid < 2688) { l = 2; start = 2560; bppShift = 3; att = a2; }
        else if (sbid < 2720) { l = 3; start = 2688; bppShift = 1; att = a3; }
        else                  { l = 4; start = 2720; bppShift = 0; att = a4; }

        int planeF4 = 1 << (18 - 2 * l);
        int bil = sbid - start;
        int chunk = bil & ((1 << bppShift) - 1);
        int nf4 = planeF4 >> bppShift;          // 2048, or 1024 at l4
        unsigned gf4base = (unsigned)(bil >> bppShift) * (unsigned)planeF4
                         + (unsigned)chunk * (unsigned)nf4 + threadIdx.x;

        if (nf4 == 2048) {
            float4 av[8];
            #pragma unroll
            for (int u = 0; u < 8; ++u)
                av[u] = reinterpret_cast<const float4*>(att)[gf4base + u * 256u];
            #pragma unroll
            for (int u = 0; u < 8; ++u) {
                float q0 = 1.0f - fminf(fmaxf(av[u].x, EPSF), 1.0f - EPSF);
                float q1 = 1.0f - fminf(fmaxf(av[u].y, EPSF), 1.0f - EPSF);
                float q2 = 1.0f - fminf(fmaxf(av[u].z, EPSF), 1.0f - EPSF);
                float q3 = 1.0f - fminf(fmaxf(av[u].w, EPSF), 1.0f - EPSF);
                s -= __logf((q0 * q1) * (q2 * q3));   // >= 1e-28, no underflow
            }
        } else {
            float4 av[4];
            #pragma unroll
            for (int u = 0; u < 4; ++u)
                av[u] = reinterpret_cast<const float4*>(att)[gf4base + u * 256u];
            #pragma unroll
            for (int u = 0; u < 4; ++u) {
                float q0 = 1.0f - fminf(fmaxf(av[u].x, EPSF), 1.0f - EPSF);
                float q1 = 1.0f - fminf(fmaxf(av[u].y, EPSF), 1.0f - EPSF);
                float q2 = 1.0f - fminf(fmaxf(av[u].z, EPSF), 1.0f - EPSF);
                float q3 = 1.0f - fminf(fmaxf(av[u].w, EPSF), 1.0f - EPSF);
                s -= __logf((q0 * q1) * (q2 * q3));
            }
        }
        float t = block_reduce(s, wsum);
        if (threadIdx.x == 0) partial[sbid] = t;
        return;
    }

    // ---------------- correction: masked px add log((1-p)/p) -----------------
    __shared__ int4 rect[N_BOX];                // x1,y1,x2,y2 (compacted)
    __shared__ int Rcnt;

    int c = bid;
    int b = c / 5, l = c % 5;
    const float* att = pick_att(l, a0, a1, a2, a3, a4);
    int wl = 1024 >> l;
    unsigned maxIdx = ((unsigned)B_SZ << (20 - 2 * l)) - 1u;
    float Wf = (float)(*wp), Hf = (float)(*hp);

    if (threadIdx.x == 0) Rcnt = 0;
    __syncthreads();

    // gate boxes, compact active rects (one lane per box; order-independent:
    // first-hit dedup makes the union a set regardless of compaction order)
    if (threadIdx.x < N_BOX) {
        int n = threadIdx.x;
        const float* bx = bboxs + (b * N_BOX + n) * 5;
        float x1 = bx[0], y1 = bx[1], x2 = bx[2], y2 = bx[3], lb = bx[4];
        double based = (double)(32 << l);
        float mn  = (float)(based * based * 0.5);
        float mxv = (float)((based * 1.58) * (based * 1.58) * 2.0);
        float area = (x2 - x1) * (y2 - y1);
        bool ok = (lb != -1.0f) && (x1 <= Wf) && (y1 <= Hf) &&
                  (x2 <= Wf) && (y2 <= Hf) && (area >= mn) && (area <= mxv);
        float sx = (float)wl / Wf, sy = (float)wl / Hf;
        int ix1 = (int)fmaxf(floorf(x1 * sx), 0.0f);
        int iy1 = (int)fmaxf(floorf(y1 * sy), 0.0f);
        int ix2 = (int)fminf(ceilf(x2 * sx) + 1.0f, (float)wl);
        int iy2 = (int)fminf(ceilf(y2 * sy) + 1.0f, (float)wl);
        if (ok && ix2 > ix1 && iy2 > iy1) {
            int i = atomicAdd(&Rcnt, 1);
            rect[i] = make_int4(ix1, iy1, ix2, iy2);
        }
    }
    __syncthreads();

    int Rc = Rcnt;
    unsigned pbase = (unsigned)b << (20 - 2 * l);

    // pair = (rect r, row slot). Typical rect is ~7..27 px/side at every level
    // (the area gate ties box size to level scale), so one row iteration and
    // one 32-px window is the common case; the loops keep any data exact.
    for (int pair = (int)threadIdx.x; pair < Rc * 32; pair += 256) {
        int r = pair >> 5, row = pair & 31;
        int4 rc = rect[r];
        int wpx = rc.z - rc.x;
        for (int y = rc.y + row; y < rc.w; y += 32) {
            unsigned rowbase = pbase + (unsigned)y * (unsigned)wl + (unsigned)rc.x;
            for (int xoff = 0; xoff < wpx; xoff += 32) {
                // window = [rc.x+xoff, rc.x+xoff+32); base interval of rect
                unsigned m = bits32(0, min(wpx - xoff, 32));
                for (int q = 0; q < r; ++q) {      // first-hit dedup (union)
                    int4 qc = rect[q];             // uniform LDS broadcast
                    bool inRow = (y >= qc.y) && (y < qc.w);
                    int ql = max(qc.x - rc.x - xoff, 0);
                    int qh = min(qc.z - rc.x - xoff, 32);
                    if (inRow && ql < qh) m &= ~bits32(ql, qh);
                }
                if (!m) continue;
                // batched independent loads: issue all 32, single wait
                float px[32];
                #pragma unroll
                for (int i = 0; i < 32; ++i) {
                    unsigned a = rowbase + (unsigned)(xoff + i);
                    px[i] = att[a < maxIdx ? a : maxIdx];
                }
                // grouped logs: ratio term (or 1.0) x4 per log; range safe:
                // (1e-7)^4 = 1e-28 > FLT_MIN, (1e7)^4 = 1e28 < FLT_MAX
                #pragma unroll
                for (int i = 0; i < 32; i += 4) {
                    float g = 1.0f;
                    #pragma unroll
                    for (int j = 0; j < 4; ++j) {
                        float p = fminf(fmaxf(px[i + j], EPSF), 1.0f - EPSF);
                        float ratio = (1.0f - p) / p;
                        g *= ((m >> (i + j)) & 1u) ? ratio : 1.0f;
                    }
                    if (g != 1.0f) s += __logf(g);
                }
            }
        }
    }

    float t = block_reduce(s, wsum);
    if (threadIdx.x == 0) corr[c] = t;
}

// ---- kernel 2: finalize ------------------------------------------------------
__global__ __launch_bounds__(256)
void finalize_kernel(const float* __restrict__ bboxs,
                     const int* __restrict__ hp, const int* __restrict__ wp,
                     const float* __restrict__ partial,
                     const float* __restrict__ corr,
                     float* __restrict__ out)
{
    __shared__ int hasbox[B_SZ];
    __shared__ double red[256];
    if (threadIdx.x < B_SZ) hasbox[threadIdx.x] = 0;
    __syncthreads();
    float Wf = (float)(*wp), Hf = (float)(*hp);
    for (int i = (int)threadIdx.x; i < B_SZ * N_BOX; i += 256) {
        const float* bx = bboxs + i * 5;
        if (bx[4] != -1.0f && bx[0] <= Wf && bx[1] <= Hf && bx[2] <= Wf && bx[3] <= Hf)
            hasbox[i / N_BOX] = 1;        // benign race, same value
    }
    __syncthreads();

    double t = 0.0;
    for (int i = (int)threadIdx.x; i < N_STREAM; i += 256) {
        int l, start, bppShift;
        if (i < 2048)      { l = 0; start = 0;    bppShift = 7; }
        else if (i < 2560) { l = 1; start = 2048; bppShift = 5; }
        else if (i < 2688) { l = 2; start = 2560; bppShift = 3; }
        else if (i < 2720) { l = 3; start = 2688; bppShift = 1; }
        else               { l = 4; start = 2720; bppShift = 0; }
        int b = (i - start) >> bppShift;
        if (hasbox[b]) {
            int wl = 1024 >> l;
            t += (double)partial[i] / (double)(wl * wl);
        }
    }
    for (int i = (int)threadIdx.x; i < N_CORR; i += 256) {
        int b = i / 5, l = i % 5;
        if (hasbox[b]) {
            int wl = 1024 >> l;
            t += (double)corr[i] / (double)(wl * wl);
        }
    }
    red[threadIdx.x] = t;
    __syncthreads();
    for (int off = 128; off > 0; off >>= 1) {
        if ((int)threadIdx.x < off) red[threadIdx.x] += red[threadIdx.x + off];
        __syncthreads();
    }
    if (threadIdx.x == 0)
        out[0] = (float)(red[0] / (5.0 * (double)B_SZ));
}

// ---- launch ------------------------------------------------------------------
extern "C" void kernel_launch(void* const* d_in, const int* in_sizes, int n_in,
                              void* d_out, int out_size, void* d_ws, size_t ws_size,
                              hipStream_t stream)
{
    const float* a0 = (const float*)d_in[0];
    const float* a1 = (const float*)d_in[1];
    const float* a2 = (const float*)d_in[2];
    const float* a3 = (const float*)d_in[3];
    const float* a4 = (const float*)d_in[4];
    const float* bboxs = (const float*)d_in[5];
    const int* hp = (const int*)d_in[6];
    const int* wp = (const int*)d_in[7];

    float* partial = (float*)d_ws;            // N_STREAM floats, all written
    float* corr    = partial + N_STREAM;      // N_CORR floats, all written

    fused_kernel<<<N_BLOCKS, 256, 0, stream>>>(a0, a1, a2, a3, a4,
                                               bboxs, hp, wp, partial, corr);
    finalize_kernel<<<1, 256, 0, stream>>>(bboxs, hp, wp, partial, corr,
                                           (float*)d_out);
}